// Round 3
// baseline (186.099 us; speedup 1.0000x reference)
//
#include <hip/hip_runtime.h>
#include <stdint.h>

typedef unsigned long long u64;
typedef uint32_t u32;

#define BB  32
#define CC  256
#define HH  56
#define WW  56
#define OHH 28
#define OWW 28
#define NPIX (BB*OHH*OWW)   // 25088

// ---------------- Kernel 0: weight prep (alpha + bit-pack) ----------------
__global__ __launch_bounds__(256) void rrb_prep_w(const float* __restrict__ w1,
                                                  const float* __restrict__ w2,
                                                  u32* __restrict__ wp1, u32* __restrict__ wp2,
                                                  float* __restrict__ alpha1, float* __restrict__ alpha2) {
    __shared__ float red[256];
    int co = blockIdx.x & 255;
    int t = threadIdx.x;            // ci
    int wid = t >> 6, lane = t & 63;
    float asum = 0.f;
    if (blockIdx.x < 256) {
        const float* wr = w1 + (size_t)co * 2304 + (size_t)t * 9;
        float v[9];
        #pragma unroll
        for (int k = 0; k < 9; ++k) { v[k] = wr[k]; asum += fabsf(v[k]); }
        #pragma unroll
        for (int k = 0; k < 9; ++k) {
            u64 m = __ballot(v[k] > 0.f);
            if (lane == 0)
                *(u64*)&wp1[((size_t)co * 9 + k) * 8 + 2 * wid] = m;
        }
    } else {
        float v = w2[co * 256 + t];
        asum = fabsf(v);
        u64 m = __ballot(v > 0.f);
        if (lane == 0) *(u64*)&wp2[co * 8 + 2 * wid] = m;
    }
    red[t] = asum; __syncthreads();
    for (int st = 128; st > 0; st >>= 1) {
        if (t < st) red[t] += red[t + st];
        __syncthreads();
    }
    if (t == 0) {
        if (blockIdx.x < 256) alpha1[co] = red[0] / 2304.f;
        else                  alpha2[co] = red[0] / 256.f;
    }
}

// ---------------- Kernel 1: pack sign(x+beta1) bits + 2x2 avgpool ----------------
// Thread = (n, oh, ow, word j). Register-stages ALL 64 float2 x-loads up front
// (static-indexed arrays -> VGPRs) so ~64 loads/wave are in flight; then computes
// bits + pool. Lane layout keeps 8 consecutive-ow lanes per channel plane -> each
// load instr covers 64B-contiguous segments per j-plane.
__global__ __launch_bounds__(256) void rrb_pack_x(const float* __restrict__ x,
                                                  const float* __restrict__ rsb1,
                                                  u32* __restrict__ xb, float* __restrict__ pool) {
    int i = blockIdx.x * 256 + threadIdx.x;   // 32*28*28*8 = 200704 threads
    int j  = i & 7;
    int t2 = i >> 3;
    int ow = t2 % OWW;
    t2 /= OWW;
    int oh = t2 % OHH;
    int n  = t2 / OHH;
    const float* base = x + (((size_t)(n * CC + 32 * j) * HH + 2 * oh) * WW + 2 * ow);

    float2 a0[32], a1[32];
    #pragma unroll
    for (int cc = 0; cc < 32; ++cc) {
        const float* p = base + (size_t)cc * (HH * WW);
        a0[cc] = *(const float2*)p;
        a1[cc] = *(const float2*)(p + WW);
    }
    float4 nb[8];
    #pragma unroll
    for (int q = 0; q < 8; ++q) nb[q] = *(const float4*)&rsb1[32 * j + 4 * q];

    u32 w00 = 0, w01 = 0, w10 = 0, w11 = 0;
    float pv[32];
    #pragma unroll
    for (int cc = 0; cc < 32; ++cc) {
        float b = ((const float*)nb)[cc];
        w00 |= (u32)(a0[cc].x + b > 0.f) << cc;
        w01 |= (u32)(a0[cc].y + b > 0.f) << cc;
        w10 |= (u32)(a1[cc].x + b > 0.f) << cc;
        w11 |= (u32)(a1[cc].y + b > 0.f) << cc;
        pv[cc] = (a0[cc].x + a0[cc].y + a1[cc].x + a1[cc].y) * 0.25f;
    }

    float* pp = pool + ((size_t)(n * OHH + oh) * OWW + ow) * CC + 32 * j;
    #pragma unroll
    for (int q = 0; q < 8; ++q)
        *(float4*)&pp[4 * q] = make_float4(pv[4 * q], pv[4 * q + 1], pv[4 * q + 2], pv[4 * q + 3]);

    u32* xo = xb + (((size_t)(n * HH + 2 * oh) * WW + 2 * ow) * 8) + j;
    xo[0] = w00;
    xo[8] = w01;
    xo[WW * 8] = w10;
    xo[WW * 8 + 8] = w11;
}

// ---------------- Kernel 2: binary conv1 (3x3, s2, p1) + bn1 stats ----------------
__global__ __launch_bounds__(256) void rrb_conv1(const u32* __restrict__ xb,
                                                 const u32* __restrict__ wp1,
                                                 short* __restrict__ S1,
                                                 int* __restrict__ s_sum, u64* __restrict__ s_sq) {
    __shared__ u32 xs[3 * WW * 8];   // 5.25 KB
    int blk = blockIdx.x;
    int n = blk / OHH, oh = blk - n * OHH;
    int t = threadIdx.x;             // co
    int r0 = 2 * oh - 1;
    for (int i = t; i < 3 * WW * 8; i += 256) {
        int row = i / (WW * 8);
        int ih = r0 + row;
        xs[i] = (ih >= 0) ? xb[((size_t)(n * HH + ih) * WW) * 8 + (i - row * WW * 8)] : 0u;
    }
    u32 wreg[72];
    {
        const u32* wsrc = wp1 + (size_t)t * 72;
        #pragma unroll
        for (int i = 0; i < 72; ++i) wreg[i] = wsrc[i];
    }
    __syncthreads();
    bool oh0 = (oh == 0);
    int bsum = 0; long long bsq = 0;
    short* outp = S1 + ((size_t)(n * OHH + oh) * OWW) * CC + t;
    for (int ow = 0; ow < OWW; ++ow) {
        int S = 0;
        #pragma unroll
        for (int kh = 0; kh < 3; ++kh) {
            bool vkh = !(kh == 0 && oh0);
            #pragma unroll
            for (int kw = 0; kw < 3; ++kw) {
                int iw = 2 * ow + kw - 1;
                bool ok = vkh && (iw >= 0);
                int iwc = iw < 0 ? 0 : iw;
                const u32* xp = &xs[(kh * WW + iwc) * 8];
                int p = 0;
                #pragma unroll
                for (int j = 0; j < 8; ++j) p += __popc(xp[j] ^ wreg[(kh * 3 + kw) * 8 + j]);
                S += ok ? (256 - 2 * p) : 0;
            }
        }
        outp[ow * CC] = (short)S;
        bsum += S;
        bsq += (long long)S * S;
    }
    atomicAdd(&s_sum[t], bsum);
    atomicAdd(&s_sq[t], (u64)bsq);
}

// ---------------- Kernel 3/6: finalize BN params from exact integer stats ----------------
__global__ void rrb_finalize(const int* __restrict__ ssum, const u64* __restrict__ ssq,
                             const float* __restrict__ alpha,
                             const float* __restrict__ gamma, const float* __restrict__ beta,
                             float* __restrict__ A, float* __restrict__ Bv) {
    int c = threadIdx.x;
    const double N = (double)NPIX;
    double s = (double)ssum[c];
    double q = (double)ssq[c];
    double mS = s / N;
    double vS = q / N - mS * mS;
    double al = (double)alpha[c];
    double mean = al * mS;
    double var = al * al * vS;
    double scale = (double)gamma[c] / sqrt(var + 1e-5);
    A[c] = (float)(al * scale);
    Bv[c] = (float)((double)beta[c] - mean * scale);
}

// ---------------- Kernel 4: out1 = rprelu(bn1+pool), pack sign(out1+beta2) ----------------
__global__ __launch_bounds__(256) void rrb_out1(const short* __restrict__ S1,
                                                float* __restrict__ pool,
                                                const float* __restrict__ A1, const float* __restrict__ B1,
                                                const float* __restrict__ pg, const float* __restrict__ pz,
                                                const float* __restrict__ ps, const float* __restrict__ rsb2,
                                                u32* __restrict__ x2b) {
    int blk = blockIdx.x;
    int n = blk / OHH, oh = blk - n * OHH;
    int c = threadIdx.x;
    int wid = c >> 6, lane = c & 63;
    float a = A1[c], b = B1[c];
    float g = pg[c], z = pz[c], s = ps[c], b2 = rsb2[c];
    const short* sp = S1 + ((size_t)(n * OHH + oh) * OWW) * CC + c;
    float* pp = pool + ((size_t)(n * OHH + oh) * OWW) * CC + c;
    u32* xo = x2b + ((size_t)(n * OHH + oh) * OWW) * 8;
    for (int ow = 0; ow < OWW; ++ow) {
        float v = a * (float)sp[ow * CC] + b + pp[ow * CC];
        float xsv = v - g;
        float o = (xsv > 0.f ? xsv : s * xsv) + z;
        pp[ow * CC] = o;
        u64 m = __ballot(o + b2 > 0.f);
        if (lane == 0) *(u64*)&xo[ow * 8 + 2 * wid] = m;
    }
}

// ---------------- Kernel 5: binary conv2 (1x1) + bn2 stats ----------------
__global__ __launch_bounds__(256) void rrb_conv2(const u32* __restrict__ x2b,
                                                 const u32* __restrict__ wp2,
                                                 short* __restrict__ S2,
                                                 int* __restrict__ s_sum, u64* __restrict__ s_sq) {
    __shared__ u32 xs[OWW * 8];      // 896 B
    int blk = blockIdx.x;
    int n = blk / OHH, oh = blk - n * OHH;
    int t = threadIdx.x;             // co
    const u32* src = x2b + ((size_t)(n * OHH + oh) * OWW) * 8;
    if (t < OWW * 8) xs[t] = src[t];
    u32 wr[8];
    {
        const u32* wsv = wp2 + (size_t)t * 8;
        #pragma unroll
        for (int j = 0; j < 8; ++j) wr[j] = wsv[j];
    }
    __syncthreads();
    int bsum = 0; long long bsq = 0;
    short* outp = S2 + ((size_t)(n * OHH + oh) * OWW) * CC + t;
    for (int ow = 0; ow < OWW; ++ow) {
        int p = 0;
        #pragma unroll
        for (int j = 0; j < 8; ++j) p += __popc(xs[ow * 8 + j] ^ wr[j]);
        int S = 256 - 2 * p;
        outp[ow * CC] = (short)S;
        bsum += S;
        bsq += (long long)S * S;
    }
    atomicAdd(&s_sum[t], bsum);
    atomicAdd(&s_sq[t], (u64)bsq);
}

// ---------------- Kernel 7: y = bn2(conv2) + out1, concat duplicate, NCHW transpose ------
__global__ __launch_bounds__(256) void rrb_final(const short* __restrict__ S2,
                                                 const float* __restrict__ out1,
                                                 const float* __restrict__ A2, const float* __restrict__ B2,
                                                 float* __restrict__ y) {
    int blk = blockIdx.x;
    int n = blk / OHH, oh = blk - n * OHH;
    int c = threadIdx.x;
    float a = A2[c], b = B2[c];
    const short* sp = S2 + ((size_t)(n * OHH + oh) * OWW) * CC + c;
    const float* op = out1 + ((size_t)(n * OHH + oh) * OWW) * CC + c;
    float buf[OWW];
    #pragma unroll
    for (int ow = 0; ow < OWW; ++ow)
        buf[ow] = a * (float)sp[ow * CC] + b + op[ow * CC];
    float* y0 = y + ((size_t)(n * 2 * CC + c) * OHH + oh) * OWW;
    float* y1 = y0 + (size_t)CC * OHH * OWW;
    #pragma unroll
    for (int k = 0; k < OWW / 4; ++k) {
        float4 v = make_float4(buf[4 * k], buf[4 * k + 1], buf[4 * k + 2], buf[4 * k + 3]);
        *(float4*)&y0[4 * k] = v;
        *(float4*)&y1[4 * k] = v;
    }
}

extern "C" void kernel_launch(void* const* d_in, const int* in_sizes, int n_in,
                              void* d_out, int out_size, void* d_ws, size_t ws_size,
                              hipStream_t stream) {
    const float* x    = (const float*)d_in[0];
    const float* rsb1 = (const float*)d_in[1];
    const float* w1   = (const float*)d_in[2];
    const float* bn1g = (const float*)d_in[3];
    const float* bn1b = (const float*)d_in[4];
    const float* rsb2 = (const float*)d_in[5];
    const float* w2   = (const float*)d_in[6];
    const float* bn2g = (const float*)d_in[7];
    const float* bn2b = (const float*)d_in[8];
    const float* pg   = (const float*)d_in[9];
    const float* pz   = (const float*)d_in[10];
    const float* ps   = (const float*)d_in[11];
    float* y = (float*)d_out;

    char* ws = (char*)d_ws;
    if (ws_size < 55488512) return;

    u32*   wp1    = (u32*)(ws + 0);          // 73728 B
    u32*   wp2    = (u32*)(ws + 73728);      // 8192 B
    float* alpha1 = (float*)(ws + 81920);
    float* alpha2 = (float*)(ws + 82944);
    float* A1     = (float*)(ws + 83968);
    float* B1     = (float*)(ws + 84992);
    float* A2     = (float*)(ws + 86016);
    float* B2     = (float*)(ws + 87040);
    int*   st1_sum = (int*)(ws + 88064);
    u64*   st1_sq  = (u64*)(ws + 89088);
    int*   st2_sum = (int*)(ws + 91136);
    u64*   st2_sq  = (u64*)(ws + 92160);
    u32*   xb   = (u32*)(ws + 94208);        // 3,211,264 B   [n][h][w][8]
    float* pool = (float*)(ws + 3305472);    // 25,690,112 B  [pix][256] (becomes out1)
    short* S1   = (short*)(ws + 28995584);   // 12,845,056 B  [pix][256]
    u32*   x2b  = (u32*)(ws + 41840640);     // 802,816 B     [pix][8]
    short* S2   = (short*)(ws + 42643456);   // 12,845,056 B  [pix][256]

    hipMemsetAsync(ws + 88064, 0, 6144, stream);

    rrb_prep_w<<<512, 256, 0, stream>>>(w1, w2, wp1, wp2, alpha1, alpha2);
    rrb_pack_x<<<(BB * OHH * OWW * 8) / 256, 256, 0, stream>>>(x, rsb1, xb, pool);
    rrb_conv1<<<BB * OHH, 256, 0, stream>>>(xb, wp1, S1, st1_sum, st1_sq);
    rrb_finalize<<<1, 256, 0, stream>>>(st1_sum, st1_sq, alpha1, bn1g, bn1b, A1, B1);
    rrb_out1<<<BB * OHH, 256, 0, stream>>>(S1, pool, A1, B1, pg, pz, ps, rsb2, x2b);
    rrb_conv2<<<BB * OHH, 256, 0, stream>>>(x2b, wp2, S2, st2_sum, st2_sq);
    rrb_finalize<<<1, 256, 0, stream>>>(st2_sum, st2_sq, alpha2, bn2g, bn2b, A2, B2);
    rrb_final<<<BB * OHH, 256, 0, stream>>>(S2, pool, A2, B2, y);
}

// Round 4
// 177.125 us; speedup vs baseline: 1.0507x; 1.0507x over previous
//
#include <hip/hip_runtime.h>
#include <stdint.h>

typedef unsigned long long u64;
typedef uint32_t u32;

#define BB  32
#define CC  256
#define HH  56
#define WW  56
#define OHH 28
#define OWW 28
#define NPIX (BB*OHH*OWW)   // 25088

// ---------------- Kernel 0: weight prep (alpha + bit-pack) ----------------
__global__ __launch_bounds__(256) void rrb_prep_w(const float* __restrict__ w1,
                                                  const float* __restrict__ w2,
                                                  u32* __restrict__ wp1, u32* __restrict__ wp2,
                                                  float* __restrict__ alpha1, float* __restrict__ alpha2) {
    __shared__ float red[256];
    int co = blockIdx.x & 255;
    int t = threadIdx.x;            // ci
    int wid = t >> 6, lane = t & 63;
    float asum = 0.f;
    if (blockIdx.x < 256) {
        const float* wr = w1 + (size_t)co * 2304 + (size_t)t * 9;
        float v[9];
        #pragma unroll
        for (int k = 0; k < 9; ++k) { v[k] = wr[k]; asum += fabsf(v[k]); }
        #pragma unroll
        for (int k = 0; k < 9; ++k) {
            u64 m = __ballot(v[k] > 0.f);
            if (lane == 0)
                *(u64*)&wp1[((size_t)co * 9 + k) * 8 + 2 * wid] = m;
        }
    } else {
        float v = w2[co * 256 + t];
        asum = fabsf(v);
        u64 m = __ballot(v > 0.f);
        if (lane == 0) *(u64*)&wp2[co * 8 + 2 * wid] = m;
    }
    red[t] = asum; __syncthreads();
    for (int st = 128; st > 0; st >>= 1) {
        if (t < st) red[t] += red[t + st];
        __syncthreads();
    }
    if (t == 0) {
        if (blockIdx.x < 256) alpha1[co] = red[0] / 2304.f;
        else                  alpha2[co] = red[0] / 256.f;
    }
}

// ---------------- Kernel 1: pack sign(x+beta1) bits + 2x2 avgpool ----------------
// Thread = (j-word, n, oh, ow, s) with s = 8-channel sub-slice (s = i&3 fastest).
// 802816 threads / 3136 blocks -> CU-saturating occupancy; each thread does 16
// float2 loads. Word assembly: 2-step shfl_xor OR-butterfly across the 4 s-lanes
// (adjacent lanes, same wave). Lane order (s,ow) -> each x-load instr covers 4
// full 128B lines.
__global__ __launch_bounds__(256) void rrb_pack_x(const float* __restrict__ x,
                                                  const float* __restrict__ rsb1,
                                                  u32* __restrict__ xb, float* __restrict__ pool) {
    int i = blockIdx.x * 256 + threadIdx.x;   // 4*28*28*32*8 = 802816
    int s  = i & 3;
    int i2 = i >> 2;
    int ow = i2 % OWW;
    int i3 = i2 / OWW;
    int oh = i3 % OHH;
    int i4 = i3 / OHH;
    int n  = i4 & 31;
    int j  = i4 >> 5;
    int c0 = 32 * j + 8 * s;
    const float* base = x + (((size_t)(n * CC + c0) * HH + 2 * oh) * WW + 2 * ow);

    float2 a0[8], a1[8];
    #pragma unroll
    for (int cc = 0; cc < 8; ++cc) {
        const float* p = base + (size_t)cc * (HH * WW);
        a0[cc] = *(const float2*)p;
        a1[cc] = *(const float2*)(p + WW);
    }
    float4 b0 = *(const float4*)&rsb1[c0];
    float4 b1 = *(const float4*)&rsb1[c0 + 4];

    u32 w00 = 0, w01 = 0, w10 = 0, w11 = 0;
    float pv[8];
    #pragma unroll
    for (int cc = 0; cc < 8; ++cc) {
        float b = (cc < 4) ? ((const float*)&b0)[cc] : ((const float*)&b1)[cc - 4];
        w00 |= (u32)(a0[cc].x + b > 0.f) << cc;
        w01 |= (u32)(a0[cc].y + b > 0.f) << cc;
        w10 |= (u32)(a1[cc].x + b > 0.f) << cc;
        w11 |= (u32)(a1[cc].y + b > 0.f) << cc;
        pv[cc] = (a0[cc].x + a0[cc].y + a1[cc].x + a1[cc].y) * 0.25f;
    }
    w00 <<= 8 * s; w01 <<= 8 * s; w10 <<= 8 * s; w11 <<= 8 * s;
    // OR-butterfly across the 4 s-lanes (lanes 4m..4m+3)
    w00 |= __shfl_xor(w00, 1); w00 |= __shfl_xor(w00, 2);
    w01 |= __shfl_xor(w01, 1); w01 |= __shfl_xor(w01, 2);
    w10 |= __shfl_xor(w10, 1); w10 |= __shfl_xor(w10, 2);
    w11 |= __shfl_xor(w11, 1); w11 |= __shfl_xor(w11, 2);

    float* pp = pool + ((size_t)(n * OHH + oh) * OWW + ow) * CC + c0;
    *(float4*)&pp[0] = make_float4(pv[0], pv[1], pv[2], pv[3]);
    *(float4*)&pp[4] = make_float4(pv[4], pv[5], pv[6], pv[7]);

    // lane s writes word s: s0->w00, s1->w01, s2->w10, s3->w11
    u32* xo = xb + (((size_t)(n * HH + 2 * oh) * WW + 2 * ow) * 8) + j;
    u32 wsel = (s == 0) ? w00 : (s == 1) ? w01 : (s == 2) ? w10 : w11;
    int off = (s == 0) ? 0 : (s == 1) ? 8 : (s == 2) ? WW * 8 : WW * 8 + 8;
    xo[off] = wsel;
}

// ---------------- Kernel 2: binary conv1 (3x3, s2, p1) + bn1 stats ----------------
__global__ __launch_bounds__(256) void rrb_conv1(const u32* __restrict__ xb,
                                                 const u32* __restrict__ wp1,
                                                 short* __restrict__ S1,
                                                 int* __restrict__ s_sum, u64* __restrict__ s_sq) {
    __shared__ u32 xs[3 * WW * 8];   // 5.25 KB
    int blk = blockIdx.x;
    int n = blk / OHH, oh = blk - n * OHH;
    int t = threadIdx.x;             // co
    int r0 = 2 * oh - 1;
    for (int i = t; i < 3 * WW * 8; i += 256) {
        int row = i / (WW * 8);
        int ih = r0 + row;
        xs[i] = (ih >= 0) ? xb[((size_t)(n * HH + ih) * WW) * 8 + (i - row * WW * 8)] : 0u;
    }
    u32 wreg[72];
    {
        const u32* wsrc = wp1 + (size_t)t * 72;
        #pragma unroll
        for (int i = 0; i < 72; ++i) wreg[i] = wsrc[i];
    }
    __syncthreads();
    bool oh0 = (oh == 0);
    int bsum = 0; long long bsq = 0;
    short* outp = S1 + ((size_t)(n * OHH + oh) * OWW) * CC + t;
    for (int ow = 0; ow < OWW; ++ow) {
        int S = 0;
        #pragma unroll
        for (int kh = 0; kh < 3; ++kh) {
            bool vkh = !(kh == 0 && oh0);
            #pragma unroll
            for (int kw = 0; kw < 3; ++kw) {
                int iw = 2 * ow + kw - 1;
                bool ok = vkh && (iw >= 0);
                int iwc = iw < 0 ? 0 : iw;
                const u32* xp = &xs[(kh * WW + iwc) * 8];
                int p = 0;
                #pragma unroll
                for (int j = 0; j < 8; ++j) p += __popc(xp[j] ^ wreg[(kh * 3 + kw) * 8 + j]);
                S += ok ? (256 - 2 * p) : 0;
            }
        }
        outp[ow * CC] = (short)S;
        bsum += S;
        bsq += (long long)S * S;
    }
    atomicAdd(&s_sum[t], bsum);
    atomicAdd(&s_sq[t], (u64)bsq);
}

// ---------------- Kernel 3/6: finalize BN params from exact integer stats ----------------
__global__ void rrb_finalize(const int* __restrict__ ssum, const u64* __restrict__ ssq,
                             const float* __restrict__ alpha,
                             const float* __restrict__ gamma, const float* __restrict__ beta,
                             float* __restrict__ A, float* __restrict__ Bv) {
    int c = threadIdx.x;
    const double N = (double)NPIX;
    double s = (double)ssum[c];
    double q = (double)ssq[c];
    double mS = s / N;
    double vS = q / N - mS * mS;
    double al = (double)alpha[c];
    double mean = al * mS;
    double var = al * al * vS;
    double scale = (double)gamma[c] / sqrt(var + 1e-5);
    A[c] = (float)(al * scale);
    Bv[c] = (float)((double)beta[c] - mean * scale);
}

// ---------------- Kernel 4: out1 = rprelu(bn1+pool), pack sign(out1+beta2) ----------------
// Block = (n, oh, ow-half of 14). Register-stages the 14 S1 + 14 pool reads up front.
__global__ __launch_bounds__(256) void rrb_out1(const short* __restrict__ S1,
                                                float* __restrict__ pool,
                                                const float* __restrict__ A1, const float* __restrict__ B1,
                                                const float* __restrict__ pg, const float* __restrict__ pz,
                                                const float* __restrict__ ps, const float* __restrict__ rsb2,
                                                u32* __restrict__ x2b) {
    int blk = blockIdx.x;
    int half = blk & 1;
    int rest = blk >> 1;
    int n = rest / OHH, oh = rest - n * OHH;
    int owlo = half * 14;
    int c = threadIdx.x;
    int wid = c >> 6, lane = c & 63;
    float a = A1[c], b = B1[c];
    float g = pg[c], z = pz[c], s = ps[c], b2 = rsb2[c];
    size_t pixbase = ((size_t)(n * OHH + oh) * OWW + owlo);
    const short* sp = S1 + pixbase * CC + c;
    float* pp = pool + pixbase * CC + c;
    u32* xo = x2b + pixbase * 8;
    float sv[14], pv[14];
    #pragma unroll
    for (int k = 0; k < 14; ++k) sv[k] = (float)sp[k * CC];
    #pragma unroll
    for (int k = 0; k < 14; ++k) pv[k] = pp[k * CC];
    #pragma unroll
    for (int k = 0; k < 14; ++k) {
        float v = a * sv[k] + b + pv[k];
        float xsv = v - g;
        float o = (xsv > 0.f ? xsv : s * xsv) + z;
        pp[k * CC] = o;
        u64 m = __ballot(o + b2 > 0.f);
        if (lane == 0) *(u64*)&xo[k * 8 + 2 * wid] = m;
    }
}

// ---------------- Kernel 5: binary conv2 (1x1) + bn2 stats ----------------
// Block = (n, oh, ow-half of 14).
__global__ __launch_bounds__(256) void rrb_conv2(const u32* __restrict__ x2b,
                                                 const u32* __restrict__ wp2,
                                                 short* __restrict__ S2,
                                                 int* __restrict__ s_sum, u64* __restrict__ s_sq) {
    __shared__ u32 xs[14 * 8];       // 448 B
    int blk = blockIdx.x;
    int half = blk & 1;
    int rest = blk >> 1;
    int n = rest / OHH, oh = rest - n * OHH;
    int owlo = half * 14;
    int t = threadIdx.x;             // co
    size_t pixbase = ((size_t)(n * OHH + oh) * OWW + owlo);
    const u32* src = x2b + pixbase * 8;
    if (t < 14 * 8) xs[t] = src[t];
    u32 wr[8];
    {
        const u32* wsv = wp2 + (size_t)t * 8;
        #pragma unroll
        for (int j = 0; j < 8; ++j) wr[j] = wsv[j];
    }
    __syncthreads();
    int bsum = 0; long long bsq = 0;
    short* outp = S2 + pixbase * CC + t;
    #pragma unroll
    for (int ow = 0; ow < 14; ++ow) {
        int p = 0;
        #pragma unroll
        for (int j = 0; j < 8; ++j) p += __popc(xs[ow * 8 + j] ^ wr[j]);
        int S = 256 - 2 * p;
        outp[ow * CC] = (short)S;
        bsum += S;
        bsq += (long long)S * S;
    }
    atomicAdd(&s_sum[t], bsum);
    atomicAdd(&s_sq[t], (u64)bsq);
}

// ---------------- Kernel 7: y = bn2(conv2) + out1, concat duplicate, NCHW transpose ------
// Block = (n, oh, ow-group) with groups of 16/12 (float4-aligned halves).
__global__ __launch_bounds__(256) void rrb_final(const short* __restrict__ S2,
                                                 const float* __restrict__ out1,
                                                 const float* __restrict__ A2, const float* __restrict__ B2,
                                                 float* __restrict__ y) {
    int blk = blockIdx.x;
    int half = blk & 1;
    int rest = blk >> 1;
    int n = rest / OHH, oh = rest - n * OHH;
    int owlo = half * 16;
    int cnt = half ? 12 : 16;
    int c = threadIdx.x;
    float a = A2[c], b = B2[c];
    size_t pixbase = ((size_t)(n * OHH + oh) * OWW + owlo);
    const short* sp = S2 + pixbase * CC + c;
    const float* op = out1 + pixbase * CC + c;
    float buf[16];
    if (half) {
        #pragma unroll
        for (int k = 0; k < 12; ++k) buf[k] = a * (float)sp[k * CC] + b + op[k * CC];
    } else {
        #pragma unroll
        for (int k = 0; k < 16; ++k) buf[k] = a * (float)sp[k * CC] + b + op[k * CC];
    }
    float* y0 = y + ((size_t)(n * 2 * CC + c) * OHH + oh) * OWW + owlo;
    float* y1 = y0 + (size_t)CC * OHH * OWW;
    int k4 = cnt / 4;
    for (int k = 0; k < k4; ++k) {
        float4 v = make_float4(buf[4 * k], buf[4 * k + 1], buf[4 * k + 2], buf[4 * k + 3]);
        *(float4*)&y0[4 * k] = v;
        *(float4*)&y1[4 * k] = v;
    }
}

extern "C" void kernel_launch(void* const* d_in, const int* in_sizes, int n_in,
                              void* d_out, int out_size, void* d_ws, size_t ws_size,
                              hipStream_t stream) {
    const float* x    = (const float*)d_in[0];
    const float* rsb1 = (const float*)d_in[1];
    const float* w1   = (const float*)d_in[2];
    const float* bn1g = (const float*)d_in[3];
    const float* bn1b = (const float*)d_in[4];
    const float* rsb2 = (const float*)d_in[5];
    const float* w2   = (const float*)d_in[6];
    const float* bn2g = (const float*)d_in[7];
    const float* bn2b = (const float*)d_in[8];
    const float* pg   = (const float*)d_in[9];
    const float* pz   = (const float*)d_in[10];
    const float* ps   = (const float*)d_in[11];
    float* y = (float*)d_out;

    char* ws = (char*)d_ws;
    if (ws_size < 55488512) return;

    u32*   wp1    = (u32*)(ws + 0);          // 73728 B
    u32*   wp2    = (u32*)(ws + 73728);      // 8192 B
    float* alpha1 = (float*)(ws + 81920);
    float* alpha2 = (float*)(ws + 82944);
    float* A1     = (float*)(ws + 83968);
    float* B1     = (float*)(ws + 84992);
    float* A2     = (float*)(ws + 86016);
    float* B2     = (float*)(ws + 87040);
    int*   st1_sum = (int*)(ws + 88064);
    u64*   st1_sq  = (u64*)(ws + 89088);
    int*   st2_sum = (int*)(ws + 91136);
    u64*   st2_sq  = (u64*)(ws + 92160);
    u32*   xb   = (u32*)(ws + 94208);        // 3,211,264 B   [n][h][w][8]
    float* pool = (float*)(ws + 3305472);    // 25,690,112 B  [pix][256] (becomes out1)
    short* S1   = (short*)(ws + 28995584);   // 12,845,056 B  [pix][256]
    u32*   x2b  = (u32*)(ws + 41840640);     // 802,816 B     [pix][8]
    short* S2   = (short*)(ws + 42643456);   // 12,845,056 B  [pix][256]

    hipMemsetAsync(ws + 88064, 0, 6144, stream);

    rrb_prep_w<<<512, 256, 0, stream>>>(w1, w2, wp1, wp2, alpha1, alpha2);
    rrb_pack_x<<<(BB * OHH * OWW * 8 * 4) / 256, 256, 0, stream>>>(x, rsb1, xb, pool);
    rrb_conv1<<<BB * OHH, 256, 0, stream>>>(xb, wp1, S1, st1_sum, st1_sq);
    rrb_finalize<<<1, 256, 0, stream>>>(st1_sum, st1_sq, alpha1, bn1g, bn1b, A1, B1);
    rrb_out1<<<BB * OHH * 2, 256, 0, stream>>>(S1, pool, A1, B1, pg, pz, ps, rsb2, x2b);
    rrb_conv2<<<BB * OHH * 2, 256, 0, stream>>>(x2b, wp2, S2, st2_sum, st2_sq);
    rrb_finalize<<<1, 256, 0, stream>>>(st2_sum, st2_sq, alpha2, bn2g, bn2b, A2, B2);
    rrb_final<<<BB * OHH * 2, 256, 0, stream>>>(S2, pool, A2, B2, y);
}

// Round 5
// 157.646 us; speedup vs baseline: 1.1805x; 1.1236x over previous
//
#include <hip/hip_runtime.h>
#include <stdint.h>

typedef unsigned long long u64;
typedef uint32_t u32;

#define BB  32
#define CC  256
#define HH  56
#define WW  56
#define OHH 28
#define OWW 28
#define NPIX (BB*OHH*OWW)   // 25088

// ---------------- Kernel 0: weight prep (alpha + bit-pack) + stats zeroing ----------------
__global__ __launch_bounds__(256) void rrb_prep_w(const float* __restrict__ w1,
                                                  const float* __restrict__ w2,
                                                  u32* __restrict__ wp1, u32* __restrict__ wp2,
                                                  float* __restrict__ alpha1, float* __restrict__ alpha2,
                                                  u32* __restrict__ stats_zero) {
    __shared__ float red[256];
    int co = blockIdx.x & 255;
    int t = threadIdx.x;            // ci
    int wid = t >> 6, lane = t & 63;
    if (blockIdx.x == 0) {          // zero 6144 B of stats (replaces hipMemsetAsync)
        #pragma unroll
        for (int k = 0; k < 6; ++k) stats_zero[k * 256 + t] = 0u;
    }
    float asum = 0.f;
    if (blockIdx.x < 256) {
        const float* wr = w1 + (size_t)co * 2304 + (size_t)t * 9;
        float v[9];
        #pragma unroll
        for (int k = 0; k < 9; ++k) { v[k] = wr[k]; asum += fabsf(v[k]); }
        #pragma unroll
        for (int k = 0; k < 9; ++k) {
            u64 m = __ballot(v[k] > 0.f);
            if (lane == 0)
                *(u64*)&wp1[((size_t)co * 9 + k) * 8 + 2 * wid] = m;
        }
    } else {
        float v = w2[co * 256 + t];
        asum = fabsf(v);
        u64 m = __ballot(v > 0.f);
        if (lane == 0) *(u64*)&wp2[co * 8 + 2 * wid] = m;
    }
    red[t] = asum; __syncthreads();
    for (int st = 128; st > 0; st >>= 1) {
        if (t < st) red[t] += red[t + st];
        __syncthreads();
    }
    if (t == 0) {
        if (blockIdx.x < 256) alpha1[co] = red[0] / 2304.f;
        else                  alpha2[co] = red[0] / 256.f;
    }
}

// ---------------- Kernel 1: pack sign(x+beta1) bits + 2x2 avgpool ----------------
// Thread = (j-word, n, oh, ow, s) with s = 8-channel sub-slice (s = i&3 fastest).
__global__ __launch_bounds__(256) void rrb_pack_x(const float* __restrict__ x,
                                                  const float* __restrict__ rsb1,
                                                  u32* __restrict__ xb, float* __restrict__ pool) {
    int i = blockIdx.x * 256 + threadIdx.x;   // 4*28*28*32*8 = 802816
    int s  = i & 3;
    int i2 = i >> 2;
    int ow = i2 % OWW;
    int i3 = i2 / OWW;
    int oh = i3 % OHH;
    int i4 = i3 / OHH;
    int n  = i4 & 31;
    int j  = i4 >> 5;
    int c0 = 32 * j + 8 * s;
    const float* base = x + (((size_t)(n * CC + c0) * HH + 2 * oh) * WW + 2 * ow);

    float2 a0[8], a1[8];
    #pragma unroll
    for (int cc = 0; cc < 8; ++cc) {
        const float* p = base + (size_t)cc * (HH * WW);
        a0[cc] = *(const float2*)p;
        a1[cc] = *(const float2*)(p + WW);
    }
    float4 b0 = *(const float4*)&rsb1[c0];
    float4 b1 = *(const float4*)&rsb1[c0 + 4];

    u32 w00 = 0, w01 = 0, w10 = 0, w11 = 0;
    float pv[8];
    #pragma unroll
    for (int cc = 0; cc < 8; ++cc) {
        float b = (cc < 4) ? ((const float*)&b0)[cc] : ((const float*)&b1)[cc - 4];
        w00 |= (u32)(a0[cc].x + b > 0.f) << cc;
        w01 |= (u32)(a0[cc].y + b > 0.f) << cc;
        w10 |= (u32)(a1[cc].x + b > 0.f) << cc;
        w11 |= (u32)(a1[cc].y + b > 0.f) << cc;
        pv[cc] = (a0[cc].x + a0[cc].y + a1[cc].x + a1[cc].y) * 0.25f;
    }
    w00 <<= 8 * s; w01 <<= 8 * s; w10 <<= 8 * s; w11 <<= 8 * s;
    w00 |= __shfl_xor(w00, 1); w00 |= __shfl_xor(w00, 2);
    w01 |= __shfl_xor(w01, 1); w01 |= __shfl_xor(w01, 2);
    w10 |= __shfl_xor(w10, 1); w10 |= __shfl_xor(w10, 2);
    w11 |= __shfl_xor(w11, 1); w11 |= __shfl_xor(w11, 2);

    float* pp = pool + ((size_t)(n * OHH + oh) * OWW + ow) * CC + c0;
    *(float4*)&pp[0] = make_float4(pv[0], pv[1], pv[2], pv[3]);
    *(float4*)&pp[4] = make_float4(pv[4], pv[5], pv[6], pv[7]);

    u32* xo = xb + (((size_t)(n * HH + 2 * oh) * WW + 2 * ow) * 8) + j;
    u32 wsel = (s == 0) ? w00 : (s == 1) ? w01 : (s == 2) ? w10 : w11;
    int off = (s == 0) ? 0 : (s == 1) ? 8 : (s == 2) ? WW * 8 : WW * 8 + 8;
    xo[off] = wsel;
}

// ---------------- Kernel 2: binary conv1 (3x3, s2, p1) + bn1 stats ----------------
__global__ __launch_bounds__(256) void rrb_conv1(const u32* __restrict__ xb,
                                                 const u32* __restrict__ wp1,
                                                 short* __restrict__ S1,
                                                 int* __restrict__ s_sum, u64* __restrict__ s_sq) {
    __shared__ u32 xs[3 * WW * 8];   // 5.25 KB
    int blk = blockIdx.x;
    int n = blk / OHH, oh = blk - n * OHH;
    int t = threadIdx.x;             // co
    int r0 = 2 * oh - 1;
    for (int i = t; i < 3 * WW * 8; i += 256) {
        int row = i / (WW * 8);
        int ih = r0 + row;
        xs[i] = (ih >= 0) ? xb[((size_t)(n * HH + ih) * WW) * 8 + (i - row * WW * 8)] : 0u;
    }
    u32 wreg[72];
    {
        const u32* wsrc = wp1 + (size_t)t * 72;
        #pragma unroll
        for (int i = 0; i < 72; ++i) wreg[i] = wsrc[i];
    }
    __syncthreads();
    bool oh0 = (oh == 0);
    int bsum = 0; long long bsq = 0;
    short* outp = S1 + ((size_t)(n * OHH + oh) * OWW) * CC + t;
    for (int ow = 0; ow < OWW; ++ow) {
        int S = 0;
        #pragma unroll
        for (int kh = 0; kh < 3; ++kh) {
            bool vkh = !(kh == 0 && oh0);
            #pragma unroll
            for (int kw = 0; kw < 3; ++kw) {
                int iw = 2 * ow + kw - 1;
                bool ok = vkh && (iw >= 0);
                int iwc = iw < 0 ? 0 : iw;
                const u32* xp = &xs[(kh * WW + iwc) * 8];
                int p = 0;
                #pragma unroll
                for (int j = 0; j < 8; ++j) p += __popc(xp[j] ^ wreg[(kh * 3 + kw) * 8 + j]);
                S += ok ? (256 - 2 * p) : 0;
            }
        }
        outp[ow * CC] = (short)S;
        bsum += S;
        bsq += (long long)S * S;
    }
    atomicAdd(&s_sum[t], bsum);
    atomicAdd(&s_sq[t], (u64)bsq);
}

// ---- BN finalize (exact integer stats -> A,B), inlined into consumers ----
__device__ __forceinline__ void bn_fold(const int* ssum, const u64* ssq,
                                        const float* alpha, const float* gamma,
                                        const float* beta, int c, float& a, float& b) {
    const double N = (double)NPIX;
    double s = (double)ssum[c];
    double q = (double)ssq[c];
    double mS = s / N;
    double vS = q / N - mS * mS;
    double al = (double)alpha[c];
    double scale = (double)gamma[c] / sqrt(al * al * vS + 1e-5);
    a = (float)(al * scale);
    b = (float)((double)beta[c] - al * mS * scale);
}

// ---------------- Kernel 4: out1 = rprelu(bn1+pool), pack sign(out1+beta2) ----------------
// Block = (n, oh, ow-half of 14). BN1 finalize folded in (per-thread, exact dp).
__global__ __launch_bounds__(256) void rrb_out1(const short* __restrict__ S1,
                                                float* __restrict__ pool,
                                                const int* __restrict__ ssum, const u64* __restrict__ ssq,
                                                const float* __restrict__ alpha1,
                                                const float* __restrict__ bn1g, const float* __restrict__ bn1b,
                                                const float* __restrict__ pg, const float* __restrict__ pz,
                                                const float* __restrict__ ps, const float* __restrict__ rsb2,
                                                u32* __restrict__ x2b) {
    int blk = blockIdx.x;
    int half = blk & 1;
    int rest = blk >> 1;
    int n = rest / OHH, oh = rest - n * OHH;
    int owlo = half * 14;
    int c = threadIdx.x;
    int wid = c >> 6, lane = c & 63;
    float a, b;
    bn_fold(ssum, ssq, alpha1, bn1g, bn1b, c, a, b);
    float g = pg[c], z = pz[c], s = ps[c], b2 = rsb2[c];
    size_t pixbase = ((size_t)(n * OHH + oh) * OWW + owlo);
    const short* sp = S1 + pixbase * CC + c;
    float* pp = pool + pixbase * CC + c;
    u32* xo = x2b + pixbase * 8;
    float sv[14], pv[14];
    #pragma unroll
    for (int k = 0; k < 14; ++k) sv[k] = (float)sp[k * CC];
    #pragma unroll
    for (int k = 0; k < 14; ++k) pv[k] = pp[k * CC];
    #pragma unroll
    for (int k = 0; k < 14; ++k) {
        float v = a * sv[k] + b + pv[k];
        float xsv = v - g;
        float o = (xsv > 0.f ? xsv : s * xsv) + z;
        pp[k * CC] = o;
        u64 m = __ballot(o + b2 > 0.f);
        if (lane == 0) *(u64*)&xo[k * 8 + 2 * wid] = m;
    }
}

// ---------------- Kernel 5: binary conv2 (1x1) + bn2 stats ----------------
__global__ __launch_bounds__(256) void rrb_conv2(const u32* __restrict__ x2b,
                                                 const u32* __restrict__ wp2,
                                                 short* __restrict__ S2,
                                                 int* __restrict__ s_sum, u64* __restrict__ s_sq) {
    __shared__ u32 xs[14 * 8];       // 448 B
    int blk = blockIdx.x;
    int half = blk & 1;
    int rest = blk >> 1;
    int n = rest / OHH, oh = rest - n * OHH;
    int owlo = half * 14;
    int t = threadIdx.x;             // co
    size_t pixbase = ((size_t)(n * OHH + oh) * OWW + owlo);
    const u32* src = x2b + pixbase * 8;
    if (t < 14 * 8) xs[t] = src[t];
    u32 wr[8];
    {
        const u32* wsv = wp2 + (size_t)t * 8;
        #pragma unroll
        for (int j = 0; j < 8; ++j) wr[j] = wsv[j];
    }
    __syncthreads();
    int bsum = 0; long long bsq = 0;
    short* outp = S2 + pixbase * CC + t;
    #pragma unroll
    for (int ow = 0; ow < 14; ++ow) {
        int p = 0;
        #pragma unroll
        for (int j = 0; j < 8; ++j) p += __popc(xs[ow * 8 + j] ^ wr[j]);
        int S = 256 - 2 * p;
        outp[ow * CC] = (short)S;
        bsum += S;
        bsq += (long long)S * S;
    }
    atomicAdd(&s_sum[t], bsum);
    atomicAdd(&s_sq[t], (u64)bsq);
}

// ---------------- Kernel 7: y = bn2(conv2) + out1, concat duplicate, NCHW transpose ------
// Block (n, oh). BN2 finalize folded in. LDS transpose: compute channel-last rows into
// padded LDS, then re-map lanes so y stores cover contiguous 112B rows (coalesced).
__global__ __launch_bounds__(256) void rrb_final(const short* __restrict__ S2,
                                                 const float* __restrict__ out1,
                                                 const int* __restrict__ ssum, const u64* __restrict__ ssq,
                                                 const float* __restrict__ alpha2,
                                                 const float* __restrict__ bn2g, const float* __restrict__ bn2b,
                                                 float* __restrict__ y) {
    __shared__ float lds[256 * 29];  // 29.7 KB, row pad 29 breaks bank conflicts
    int blk = blockIdx.x;
    int n = blk / OHH, oh = blk - n * OHH;
    int c = threadIdx.x;
    float a, b;
    bn_fold(ssum, ssq, alpha2, bn2g, bn2b, c, a, b);
    size_t pixbase = ((size_t)(n * OHH + oh) * OWW);
    const short* sp = S2 + pixbase * CC + c;
    const float* op = out1 + pixbase * CC + c;
    #pragma unroll
    for (int ow = 0; ow < OWW; ++ow)
        lds[c * 29 + ow] = a * (float)sp[ow * CC] + b + op[ow * CC];
    __syncthreads();
    #pragma unroll
    for (int it = 0; it < 7; ++it) {
        int idx = it * 256 + c;        // 0..1791 = 256 rows x 7 float4
        int cp = idx / 7, qq = idx - cp * 7;
        const float* lp = &lds[cp * 29 + 4 * qq];
        float4 v = make_float4(lp[0], lp[1], lp[2], lp[3]);
        float* dst = y + ((size_t)(n * 2 * CC + cp) * OHH + oh) * OWW + 4 * qq;
        *(float4*)dst = v;
        *(float4*)(dst + (size_t)CC * OHH * OWW) = v;
    }
}

extern "C" void kernel_launch(void* const* d_in, const int* in_sizes, int n_in,
                              void* d_out, int out_size, void* d_ws, size_t ws_size,
                              hipStream_t stream) {
    const float* x    = (const float*)d_in[0];
    const float* rsb1 = (const float*)d_in[1];
    const float* w1   = (const float*)d_in[2];
    const float* bn1g = (const float*)d_in[3];
    const float* bn1b = (const float*)d_in[4];
    const float* rsb2 = (const float*)d_in[5];
    const float* w2   = (const float*)d_in[6];
    const float* bn2g = (const float*)d_in[7];
    const float* bn2b = (const float*)d_in[8];
    const float* pg   = (const float*)d_in[9];
    const float* pz   = (const float*)d_in[10];
    const float* ps   = (const float*)d_in[11];
    float* y = (float*)d_out;

    char* ws = (char*)d_ws;
    if (ws_size < 55488512) return;

    u32*   wp1    = (u32*)(ws + 0);          // 73728 B
    u32*   wp2    = (u32*)(ws + 73728);      // 8192 B
    float* alpha1 = (float*)(ws + 81920);
    float* alpha2 = (float*)(ws + 82944);
    int*   st1_sum = (int*)(ws + 88064);     // 1024 B
    u64*   st1_sq  = (u64*)(ws + 89088);     // 2048 B
    int*   st2_sum = (int*)(ws + 91136);     // 1024 B
    u64*   st2_sq  = (u64*)(ws + 92160);     // 2048 B  (stats: 6144 B total @88064)
    u32*   xb   = (u32*)(ws + 94208);        // 3,211,264 B   [n][h][w][8]
    float* pool = (float*)(ws + 3305472);    // 25,690,112 B  [pix][256] (becomes out1)
    short* S1   = (short*)(ws + 28995584);   // 12,845,056 B  [pix][256]
    u32*   x2b  = (u32*)(ws + 41840640);     // 802,816 B     [pix][8]
    short* S2   = (short*)(ws + 42643456);   // 12,845,056 B  [pix][256]

    rrb_prep_w<<<512, 256, 0, stream>>>(w1, w2, wp1, wp2, alpha1, alpha2,
                                        (u32*)(ws + 88064));
    rrb_pack_x<<<(BB * OHH * OWW * 8 * 4) / 256, 256, 0, stream>>>(x, rsb1, xb, pool);
    rrb_conv1<<<BB * OHH, 256, 0, stream>>>(xb, wp1, S1, st1_sum, st1_sq);
    rrb_out1<<<BB * OHH * 2, 256, 0, stream>>>(S1, pool, st1_sum, st1_sq, alpha1,
                                               bn1g, bn1b, pg, pz, ps, rsb2, x2b);
    rrb_conv2<<<BB * OHH * 2, 256, 0, stream>>>(x2b, wp2, S2, st2_sum, st2_sq);
    rrb_final<<<BB * OHH, 256, 0, stream>>>(S2, pool, st2_sum, st2_sq, alpha2,
                                            bn2g, bn2b, y);
}

// Round 6
// 149.573 us; speedup vs baseline: 1.2442x; 1.0540x over previous
//
#include <hip/hip_runtime.h>
#include <stdint.h>

typedef unsigned long long u64;
typedef uint32_t u32;

#define BB  32
#define CC  256
#define HH  56
#define WW  56
#define OHH 28
#define OWW 28
#define NPIX (BB*OHH*OWW)   // 25088

// ---------------- Kernel 0: weight prep (alpha + bit-pack) + stats zeroing ----------------
__global__ __launch_bounds__(256) void rrb_prep_w(const float* __restrict__ w1,
                                                  const float* __restrict__ w2,
                                                  u32* __restrict__ wp1, u32* __restrict__ wp2,
                                                  float* __restrict__ alpha1, float* __restrict__ alpha2,
                                                  u32* __restrict__ stats_zero) {
    __shared__ float red[256];
    int co = blockIdx.x & 255;
    int t = threadIdx.x;            // ci
    int wid = t >> 6, lane = t & 63;
    if (blockIdx.x == 0) {          // zero 6144 B of stats (replaces hipMemsetAsync)
        #pragma unroll
        for (int k = 0; k < 6; ++k) stats_zero[k * 256 + t] = 0u;
    }
    float asum = 0.f;
    if (blockIdx.x < 256) {
        const float* wr = w1 + (size_t)co * 2304 + (size_t)t * 9;
        float v[9];
        #pragma unroll
        for (int k = 0; k < 9; ++k) { v[k] = wr[k]; asum += fabsf(v[k]); }
        #pragma unroll
        for (int k = 0; k < 9; ++k) {
            u64 m = __ballot(v[k] > 0.f);
            if (lane == 0)
                *(u64*)&wp1[((size_t)co * 9 + k) * 8 + 2 * wid] = m;
        }
    } else {
        float v = w2[co * 256 + t];
        asum = fabsf(v);
        u64 m = __ballot(v > 0.f);
        if (lane == 0) *(u64*)&wp2[co * 8 + 2 * wid] = m;
    }
    red[t] = asum; __syncthreads();
    for (int st = 128; st > 0; st >>= 1) {
        if (t < st) red[t] += red[t + st];
        __syncthreads();
    }
    if (t == 0) {
        if (blockIdx.x < 256) alpha1[co] = red[0] / 2304.f;
        else                  alpha2[co] = red[0] / 256.f;
    }
}

// ---------------- Kernel 1: pack sign(x+beta1) bits + 2x2 avgpool ----------------
// Thread = (j-word, n, oh, ow, s) with s = 8-channel sub-slice (s = i&3 fastest).
__global__ __launch_bounds__(256) void rrb_pack_x(const float* __restrict__ x,
                                                  const float* __restrict__ rsb1,
                                                  u32* __restrict__ xb, float* __restrict__ pool) {
    int i = blockIdx.x * 256 + threadIdx.x;   // 4*28*28*32*8 = 802816
    int s  = i & 3;
    int i2 = i >> 2;
    int ow = i2 % OWW;
    int i3 = i2 / OWW;
    int oh = i3 % OHH;
    int i4 = i3 / OHH;
    int n  = i4 & 31;
    int j  = i4 >> 5;
    int c0 = 32 * j + 8 * s;
    const float* base = x + (((size_t)(n * CC + c0) * HH + 2 * oh) * WW + 2 * ow);

    float2 a0[8], a1[8];
    #pragma unroll
    for (int cc = 0; cc < 8; ++cc) {
        const float* p = base + (size_t)cc * (HH * WW);
        a0[cc] = *(const float2*)p;
        a1[cc] = *(const float2*)(p + WW);
    }
    float4 b0 = *(const float4*)&rsb1[c0];
    float4 b1 = *(const float4*)&rsb1[c0 + 4];

    u32 w00 = 0, w01 = 0, w10 = 0, w11 = 0;
    float pv[8];
    #pragma unroll
    for (int cc = 0; cc < 8; ++cc) {
        float b = (cc < 4) ? ((const float*)&b0)[cc] : ((const float*)&b1)[cc - 4];
        w00 |= (u32)(a0[cc].x + b > 0.f) << cc;
        w01 |= (u32)(a0[cc].y + b > 0.f) << cc;
        w10 |= (u32)(a1[cc].x + b > 0.f) << cc;
        w11 |= (u32)(a1[cc].y + b > 0.f) << cc;
        pv[cc] = (a0[cc].x + a0[cc].y + a1[cc].x + a1[cc].y) * 0.25f;
    }
    w00 <<= 8 * s; w01 <<= 8 * s; w10 <<= 8 * s; w11 <<= 8 * s;
    w00 |= __shfl_xor(w00, 1); w00 |= __shfl_xor(w00, 2);
    w01 |= __shfl_xor(w01, 1); w01 |= __shfl_xor(w01, 2);
    w10 |= __shfl_xor(w10, 1); w10 |= __shfl_xor(w10, 2);
    w11 |= __shfl_xor(w11, 1); w11 |= __shfl_xor(w11, 2);

    float* pp = pool + ((size_t)(n * OHH + oh) * OWW + ow) * CC + c0;
    *(float4*)&pp[0] = make_float4(pv[0], pv[1], pv[2], pv[3]);
    *(float4*)&pp[4] = make_float4(pv[4], pv[5], pv[6], pv[7]);

    u32* xo = xb + (((size_t)(n * HH + 2 * oh) * WW + 2 * ow) * 8) + j;
    u32 wsel = (s == 0) ? w00 : (s == 1) ? w01 : (s == 2) ? w10 : w11;
    int off = (s == 0) ? 0 : (s == 1) ? 8 : (s == 2) ? WW * 8 : WW * 8 + 8;
    xo[off] = wsel;
}

// ---------------- Kernel 2: binary conv1 (3x3, s2, p1) + bn1 stats ----------------
__global__ __launch_bounds__(256) void rrb_conv1(const u32* __restrict__ xb,
                                                 const u32* __restrict__ wp1,
                                                 short* __restrict__ S1,
                                                 int* __restrict__ s_sum, u64* __restrict__ s_sq) {
    __shared__ u32 xs[3 * WW * 8];   // 5.25 KB
    int blk = blockIdx.x;
    int n = blk / OHH, oh = blk - n * OHH;
    int t = threadIdx.x;             // co
    int r0 = 2 * oh - 1;
    for (int i = t; i < 3 * WW * 8; i += 256) {
        int row = i / (WW * 8);
        int ih = r0 + row;
        xs[i] = (ih >= 0) ? xb[((size_t)(n * HH + ih) * WW) * 8 + (i - row * WW * 8)] : 0u;
    }
    u32 wreg[72];
    {
        const u32* wsrc = wp1 + (size_t)t * 72;
        #pragma unroll
        for (int i = 0; i < 72; ++i) wreg[i] = wsrc[i];
    }
    __syncthreads();
    bool oh0 = (oh == 0);
    int bsum = 0; long long bsq = 0;
    short* outp = S1 + ((size_t)(n * OHH + oh) * OWW) * CC + t;
    for (int ow = 0; ow < OWW; ++ow) {
        int S = 0;
        #pragma unroll
        for (int kh = 0; kh < 3; ++kh) {
            bool vkh = !(kh == 0 && oh0);
            #pragma unroll
            for (int kw = 0; kw < 3; ++kw) {
                int iw = 2 * ow + kw - 1;
                bool ok = vkh && (iw >= 0);
                int iwc = iw < 0 ? 0 : iw;
                const u32* xp = &xs[(kh * WW + iwc) * 8];
                int p = 0;
                #pragma unroll
                for (int j = 0; j < 8; ++j) p += __popc(xp[j] ^ wreg[(kh * 3 + kw) * 8 + j]);
                S += ok ? (256 - 2 * p) : 0;
            }
        }
        outp[ow * CC] = (short)S;
        bsum += S;
        bsq += (long long)S * S;
    }
    atomicAdd(&s_sum[t], bsum);
    atomicAdd(&s_sq[t], (u64)bsq);
}

// ---- BN finalize (exact integer stats -> A,B), inlined into consumers ----
__device__ __forceinline__ void bn_fold(const int* ssum, const u64* ssq,
                                        const float* alpha, const float* gamma,
                                        const float* beta, int c, float& a, float& b) {
    const double N = (double)NPIX;
    double s = (double)ssum[c];
    double q = (double)ssq[c];
    double mS = s / N;
    double vS = q / N - mS * mS;
    double al = (double)alpha[c];
    double scale = (double)gamma[c] / sqrt(al * al * vS + 1e-5);
    a = (float)(al * scale);
    b = (float)((double)beta[c] - al * mS * scale);
}

// ---------------- Kernel 3: out1 = rprelu(bn1+pool) (in-place) + conv2 bn2-stats ----------
// Block = (n, oh, ow-half of 14). Phase A: thread=c computes out1 for 14 pixels, stores
// in-place, ballots sign(out1+beta2) bits into LDS. Phase B: thread=co does the 1x1
// binary conv from LDS bits -> integer stats only (S2 is recomputed in rrb_final).
__global__ __launch_bounds__(256) void rrb_out1c2(const short* __restrict__ S1,
                                                  float* __restrict__ pool,
                                                  const int* __restrict__ ssum, const u64* __restrict__ ssq,
                                                  const float* __restrict__ alpha1,
                                                  const float* __restrict__ bn1g, const float* __restrict__ bn1b,
                                                  const float* __restrict__ pg, const float* __restrict__ pz,
                                                  const float* __restrict__ ps, const float* __restrict__ rsb2,
                                                  const u32* __restrict__ wp2,
                                                  int* __restrict__ s_sum2, u64* __restrict__ s_sq2) {
    __shared__ u32 xs[14 * 8];       // 448 B of sign bits
    int blk = blockIdx.x;
    int half = blk & 1;
    int rest = blk >> 1;
    int n = rest / OHH, oh = rest - n * OHH;
    int owlo = half * 14;
    int c = threadIdx.x;
    int wid = c >> 6, lane = c & 63;
    float a, b;
    bn_fold(ssum, ssq, alpha1, bn1g, bn1b, c, a, b);
    float g = pg[c], z = pz[c], s = ps[c], b2 = rsb2[c];
    size_t pixbase = ((size_t)(n * OHH + oh) * OWW + owlo);
    const short* sp = S1 + pixbase * CC + c;
    float* pp = pool + pixbase * CC + c;
    float sv[14], pv[14];
    #pragma unroll
    for (int k = 0; k < 14; ++k) sv[k] = (float)sp[k * CC];
    #pragma unroll
    for (int k = 0; k < 14; ++k) pv[k] = pp[k * CC];
    #pragma unroll
    for (int k = 0; k < 14; ++k) {
        float v = a * sv[k] + b + pv[k];
        float xsv = v - g;
        float o = (xsv > 0.f ? xsv : s * xsv) + z;
        pp[k * CC] = o;
        u64 m = __ballot(o + b2 > 0.f);
        if (lane == 0) *(u64*)&xs[k * 8 + 2 * wid] = m;
    }
    __syncthreads();
    // Phase B: 1x1 binary conv -> stats only
    u32 wr[8];
    {
        const u32* wsv = wp2 + (size_t)c * 8;
        #pragma unroll
        for (int j = 0; j < 8; ++j) wr[j] = wsv[j];
    }
    int bsum = 0; long long bsq = 0;
    #pragma unroll
    for (int k = 0; k < 14; ++k) {
        int p = 0;
        #pragma unroll
        for (int j = 0; j < 8; ++j) p += __popc(xs[k * 8 + j] ^ wr[j]);
        int S = 256 - 2 * p;
        bsum += S;
        bsq += (long long)S * S;
    }
    atomicAdd(&s_sum2[c], bsum);
    atomicAdd(&s_sq2[c], (u64)bsq);
}

// ---------------- Kernel 4: recompute conv2 from out1, y = bn2 + out1, concat ----------
// Block (n, oh). Reads out1 (28 pix, coalesced), re-ballots the SAME sign bits as
// kernel 3 (same f32 values -> bit-identical), recomputes S, applies bn2 (folded from
// exact stats), adds out1, LDS-transposes, writes y twice (concat) coalesced.
__global__ __launch_bounds__(256) void rrb_final(const float* __restrict__ out1,
                                                 const int* __restrict__ ssum, const u64* __restrict__ ssq,
                                                 const float* __restrict__ alpha2,
                                                 const float* __restrict__ bn2g, const float* __restrict__ bn2b,
                                                 const float* __restrict__ rsb2,
                                                 const u32* __restrict__ wp2,
                                                 float* __restrict__ y) {
    __shared__ u32 xs[OWW * 8];      // 896 B of sign bits
    __shared__ float lds[256 * 29];  // 29.7 KB transpose buffer (pad 29)
    int blk = blockIdx.x;
    int n = blk / OHH, oh = blk - n * OHH;
    int c = threadIdx.x;
    int wid = c >> 6, lane = c & 63;
    float a, b;
    bn_fold(ssum, ssq, alpha2, bn2g, bn2b, c, a, b);
    float b2 = rsb2[c];
    size_t pixbase = ((size_t)(n * OHH + oh) * OWW);
    const float* op = out1 + pixbase * CC + c;
    float ov[OWW];
    #pragma unroll
    for (int ow = 0; ow < OWW; ++ow) ov[ow] = op[ow * CC];
    #pragma unroll
    for (int ow = 0; ow < OWW; ++ow) {
        u64 m = __ballot(ov[ow] + b2 > 0.f);
        if (lane == 0) *(u64*)&xs[ow * 8 + 2 * wid] = m;
    }
    u32 wr[8];
    {
        const u32* wsv = wp2 + (size_t)c * 8;
        #pragma unroll
        for (int j = 0; j < 8; ++j) wr[j] = wsv[j];
    }
    __syncthreads();
    #pragma unroll
    for (int ow = 0; ow < OWW; ++ow) {
        int p = 0;
        #pragma unroll
        for (int j = 0; j < 8; ++j) p += __popc(xs[ow * 8 + j] ^ wr[j]);
        int S = 256 - 2 * p;
        lds[c * 29 + ow] = a * (float)S + b + ov[ow];
    }
    __syncthreads();
    #pragma unroll
    for (int it = 0; it < 7; ++it) {
        int idx = it * 256 + c;        // 0..1791 = 256 rows x 7 float4
        int cp = idx / 7, qq = idx - cp * 7;
        const float* lp = &lds[cp * 29 + 4 * qq];
        float4 v = make_float4(lp[0], lp[1], lp[2], lp[3]);
        float* dst = y + ((size_t)(n * 2 * CC + cp) * OHH + oh) * OWW + 4 * qq;
        *(float4*)dst = v;
        *(float4*)(dst + (size_t)CC * OHH * OWW) = v;
    }
}

extern "C" void kernel_launch(void* const* d_in, const int* in_sizes, int n_in,
                              void* d_out, int out_size, void* d_ws, size_t ws_size,
                              hipStream_t stream) {
    const float* x    = (const float*)d_in[0];
    const float* rsb1 = (const float*)d_in[1];
    const float* w1   = (const float*)d_in[2];
    const float* bn1g = (const float*)d_in[3];
    const float* bn1b = (const float*)d_in[4];
    const float* rsb2 = (const float*)d_in[5];
    const float* w2   = (const float*)d_in[6];
    const float* bn2g = (const float*)d_in[7];
    const float* bn2b = (const float*)d_in[8];
    const float* pg   = (const float*)d_in[9];
    const float* pz   = (const float*)d_in[10];
    const float* ps   = (const float*)d_in[11];
    float* y = (float*)d_out;

    char* ws = (char*)d_ws;
    if (ws_size < 41840640) return;

    u32*   wp1    = (u32*)(ws + 0);          // 73728 B
    u32*   wp2    = (u32*)(ws + 73728);      // 8192 B
    float* alpha1 = (float*)(ws + 81920);
    float* alpha2 = (float*)(ws + 82944);
    int*   st1_sum = (int*)(ws + 88064);     // 1024 B
    u64*   st1_sq  = (u64*)(ws + 89088);     // 2048 B
    int*   st2_sum = (int*)(ws + 91136);     // 1024 B
    u64*   st2_sq  = (u64*)(ws + 92160);     // 2048 B  (stats: 6144 B total @88064)
    u32*   xb   = (u32*)(ws + 94208);        // 3,211,264 B   [n][h][w][8]
    float* pool = (float*)(ws + 3305472);    // 25,690,112 B  [pix][256] (becomes out1)
    short* S1   = (short*)(ws + 28995584);   // 12,845,056 B  [pix][256] -> end 41,840,640

    rrb_prep_w<<<512, 256, 0, stream>>>(w1, w2, wp1, wp2, alpha1, alpha2,
                                        (u32*)(ws + 88064));
    rrb_pack_x<<<(BB * OHH * OWW * 8 * 4) / 256, 256, 0, stream>>>(x, rsb1, xb, pool);
    rrb_conv1<<<BB * OHH, 256, 0, stream>>>(xb, wp1, S1, st1_sum, st1_sq);
    rrb_out1c2<<<BB * OHH * 2, 256, 0, stream>>>(S1, pool, st1_sum, st1_sq, alpha1,
                                                 bn1g, bn1b, pg, pz, ps, rsb2,
                                                 wp2, st2_sum, st2_sq);
    rrb_final<<<BB * OHH, 256, 0, stream>>>(pool, st2_sum, st2_sq, alpha2,
                                            bn2g, bn2b, rsb2, wp2, y);
}